// Round 4
// baseline (21508.554 us; speedup 1.0000x reference)
//
#include <hip/hip_runtime.h>
#include <math.h>

// 2-layer LSTM, B=64, T=512, F=256, H=512, fp32 — persistent cooperative kernel.
// R4 changes vs R3 (which sat at 36.5us/step, VALUBusy 11.5%):
//  1. All-report grid barrier: block i stores monotonic token (s+1) to its OWN
//     slot (256 parallel stores, NO same-address RMW chain — R3's fetch_add on
//     one line serialized ~256x ~100ns = ~25us/step). Wave 0 of every block
//     polls all 256 slots (4 coalesced relaxed-agent loads/lane + __all).
//  2. Weights are step-invariant -> staged to LDS once before the T-loop
//     (48/64 KB per block). Inner loop reads via ds_read_b128 at wave-uniform
//     addresses (same-address broadcast, conflict-free), removing the per-step
//     s_load L2-latency chain (~5-8us/step).
// h exchange stays coherent (relaxed AGENT atomics, bypass L1/L2, meet at L3);
// c block-private cached; out write-only cached; ordering from __syncthreads'
// vmcnt(0) drain before the arrival-token store (same guarantee R3 passed on).
//
// Partition (verified R1-R3): blocks[0,128)=layer0, [128,256)=layer1;
// 4 hidden units (16 gate rows) per block; 8 waves split K; lane = batch b.
// h state transposed+4-blocked: hT[k/4][b][4].

#define TT 512
#define FF 256
#define HH 512
#define NB 256

__device__ __forceinline__ float sigmoidf_(float v) {
    return 1.0f / (1.0f + __expf(-v));
}

__device__ __forceinline__ float ldg_coh(const float* p) {
    return __hip_atomic_load(p, __ATOMIC_RELAXED, __HIP_MEMORY_SCOPE_AGENT);
}
__device__ __forceinline__ void stg_coh(float* p, float v) {
    __hip_atomic_store(p, v, __ATOMIC_RELAXED, __HIP_MEMORY_SCOPE_AGENT);
}
__device__ __forceinline__ int ld_slot(const int* p) {
    return __hip_atomic_load(p, __ATOMIC_RELAXED, __HIP_MEMORY_SCOPE_AGENT);
}

__global__ void __launch_bounds__(512, 2) lstm_persist(
    const float* __restrict__ x,
    const float* __restrict__ Wih0, const float* __restrict__ Whh0,
    const float* __restrict__ bi0,  const float* __restrict__ bh0,
    const float* __restrict__ Wih1, const float* __restrict__ Whh1,
    const float* __restrict__ bi1,  const float* __restrict__ bh1,
    float* __restrict__ h0T, float* __restrict__ c0,
    float* __restrict__ h1T, float* __restrict__ c1,
    float* __restrict__ out, int* __restrict__ slots)
{
    const int layer = blockIdx.x >> 7;
    const int tile  = blockIdx.x & 127;
    const int ub    = tile << 2;          // 4 hidden units per block
    const int tid   = threadIdx.x;
    const int lane  = tid & 63;           // = batch index b
    const int wv    = __builtin_amdgcn_readfirstlane(tid >> 6);  // wave id, uniform

    __shared__ float gsh[16][64];         // [g*4+ul][b] gate pre-activations
    __shared__ float wlds[16 * 1024];     // A[16][KA] | B[16][512]  (<= 64 KB)
    __shared__ float bb[16];              // combined bias per gate row

    // ---- one-time staging: weights + bias into LDS (step-invariant) ----
    {
        const float* WA = layer ? Wih1 : Wih0;   // row stride = KA
        const float* WB = layer ? Whh1 : Whh0;   // row stride = 512
        const int KA = layer ? 512 : 256;
        const int q4 = KA >> 2;                  // float4s per A row
        for (int i = tid; i < 16 * q4; i += 512) {
            const int j = i / q4, kq = i % q4;
            const int jg = ((j >> 2) << 9) + ub + (j & 3);
            *(float4*)(wlds + j * KA + 4 * kq) =
                *(const float4*)(WA + (size_t)jg * KA + 4 * kq);
        }
        float* wB = wlds + 16 * KA;
        for (int i = tid; i < 2048; i += 512) {  // 16*512/4
            const int j = i >> 7, kq = i & 127;
            const int jg = ((j >> 2) << 9) + ub + (j & 3);
            *(float4*)(wB + j * 512 + 4 * kq) =
                *(const float4*)(WB + (size_t)jg * HH + 4 * kq);
        }
        if (tid < 16) {
            const int jg = ((tid >> 2) << 9) + ub + (tid & 3);
            bb[tid] = (layer ? bi1 : bi0)[jg] + (layer ? bh1 : bh0)[jg];
        }
    }
    __syncthreads();

    const int KA  = layer ? 512 : 256;
    const float* wA = wlds;               // [16][KA]
    const float* wB = wlds + 16 * KA;     // [16][512]

    for (int s = 0; s <= TT; ++s) {
        const bool active = layer ? (s > 0) : (s < TT);
        if (active) {
            const int t = layer ? (s - 1) : s;

            // init gates with combined bias (from LDS)
            for (int q = tid; q < 16 * 64; q += 512) {
                gsh[q >> 6][q & 63] = bb[q >> 6];
            }

            float acc[16];
#pragma unroll
            for (int j = 0; j < 16; ++j) acc[j] = 0.0f;

            const int kh0 = wv * 64;
            float hl[64];

            if (layer == 0) {
                // ---- segment A: x_t @ Wih0^T, K=256; wave slice [wv*32,+32)
                const float* xrow = x + ((size_t)lane * TT + t) * FF;
                const int kx0 = wv * 32;
#pragma unroll
                for (int kc = 0; kc < 32; kc += 4) {
                    const int k = kx0 + kc;
                    const float4 hv = *(const float4*)(xrow + k);
#pragma unroll
                    for (int j = 0; j < 16; ++j) {
                        const float4 wr = *(const float4*)(wA + j * 256 + k);  // ds_read_b128, broadcast
                        acc[j] = fmaf(hv.x, wr.x, acc[j]);
                        acc[j] = fmaf(hv.y, wr.y, acc[j]);
                        acc[j] = fmaf(hv.z, wr.z, acc[j]);
                        acc[j] = fmaf(hv.w, wr.w, acc[j]);
                    }
                }
                // ---- segment B: h0[t-1] @ Whh0^T; coherent h loads, hoisted
                const float* hb = h0T + (((t + 1) & 1) << 15)
                                + ((kh0 >> 2) << 8) + (lane << 2);
#pragma unroll
                for (int q = 0; q < 16; ++q) {
                    const float* p = hb + (q << 8);
                    hl[4*q+0] = ldg_coh(p+0);
                    hl[4*q+1] = ldg_coh(p+1);
                    hl[4*q+2] = ldg_coh(p+2);
                    hl[4*q+3] = ldg_coh(p+3);
                }
#pragma unroll
                for (int q = 0; q < 16; ++q) {
                    const int k = kh0 + 4 * q;
#pragma unroll
                    for (int j = 0; j < 16; ++j) {
                        const float4 wr = *(const float4*)(wB + j * 512 + k);
                        acc[j] = fmaf(hl[4*q+0], wr.x, acc[j]);
                        acc[j] = fmaf(hl[4*q+1], wr.y, acc[j]);
                        acc[j] = fmaf(hl[4*q+2], wr.z, acc[j]);
                        acc[j] = fmaf(hl[4*q+3], wr.w, acc[j]);
                    }
                }
            } else {
                // ---- layer1 @ t=s-1: segment A input = h0[t] (coherent)
                const float* hb0 = h0T + (((s - 1) & 1) << 15)
                                 + ((kh0 >> 2) << 8) + (lane << 2);
#pragma unroll
                for (int q = 0; q < 16; ++q) {
                    const float* p = hb0 + (q << 8);
                    hl[4*q+0] = ldg_coh(p+0);
                    hl[4*q+1] = ldg_coh(p+1);
                    hl[4*q+2] = ldg_coh(p+2);
                    hl[4*q+3] = ldg_coh(p+3);
                }
#pragma unroll
                for (int q = 0; q < 16; ++q) {
                    const int k = kh0 + 4 * q;
#pragma unroll
                    for (int j = 0; j < 16; ++j) {
                        const float4 wr = *(const float4*)(wA + j * 512 + k);
                        acc[j] = fmaf(hl[4*q+0], wr.x, acc[j]);
                        acc[j] = fmaf(hl[4*q+1], wr.y, acc[j]);
                        acc[j] = fmaf(hl[4*q+2], wr.z, acc[j]);
                        acc[j] = fmaf(hl[4*q+3], wr.w, acc[j]);
                    }
                }
                // ---- segment B: h1[t-1] (coherent)
                const float* hb1 = h1T + ((s & 1) << 15)
                                 + ((kh0 >> 2) << 8) + (lane << 2);
#pragma unroll
                for (int q = 0; q < 16; ++q) {
                    const float* p = hb1 + (q << 8);
                    hl[4*q+0] = ldg_coh(p+0);
                    hl[4*q+1] = ldg_coh(p+1);
                    hl[4*q+2] = ldg_coh(p+2);
                    hl[4*q+3] = ldg_coh(p+3);
                }
#pragma unroll
                for (int q = 0; q < 16; ++q) {
                    const int k = kh0 + 4 * q;
#pragma unroll
                    for (int j = 0; j < 16; ++j) {
                        const float4 wr = *(const float4*)(wB + j * 512 + k);
                        acc[j] = fmaf(hl[4*q+0], wr.x, acc[j]);
                        acc[j] = fmaf(hl[4*q+1], wr.y, acc[j]);
                        acc[j] = fmaf(hl[4*q+2], wr.z, acc[j]);
                        acc[j] = fmaf(hl[4*q+3], wr.w, acc[j]);
                    }
                }
            }

            __syncthreads();
#pragma unroll
            for (int j = 0; j < 16; ++j) atomicAdd(&gsh[j][lane], acc[j]);
            __syncthreads();

            if (tid < 256) {               // 4 u x 64 b state updates
                const int b  = tid & 63;
                const int ul = tid >> 6;
                const int u  = ub + ul;
                const float iv = sigmoidf_(gsh[ul][b]);
                const float fv = sigmoidf_(gsh[4 + ul][b]);
                const float gv = tanhf(gsh[8 + ul][b]);
                const float ov = sigmoidf_(gsh[12 + ul][b]);
                float* cbuf = layer ? c1 : c0;          // block-private: cached
                const size_t ci = ((size_t)b << 9) + u;
                const float cn = fv * cbuf[ci] + iv * gv;
                cbuf[ci] = cn;
                const float hn = ov * tanhf(cn);
                float* hTn = layer ? (h1T + (((s - 1) & 1) << 15))
                                   : (h0T + ((s & 1) << 15));
                stg_coh(hTn + ((size_t)tile << 8) + (b << 2) + ul, hn);
                if (layer) out[(((size_t)b * TT) + t) * HH + u] = hn;  // write-only: cached
            }
        }

        // ---- all-report grid barrier: parallel token stores, no RMWs ----
        // __syncthreads drains vmcnt(0): coherent h stores are acked at the
        // coherence point before the arrival token is issued.
        __syncthreads();
        if (tid == 0)
            __hip_atomic_store(&slots[blockIdx.x], s + 1,
                               __ATOMIC_RELAXED, __HIP_MEMORY_SCOPE_AGENT);
        if (tid < 64) {
            const int tgt = s + 1;
            for (;;) {
                const int v0 = ld_slot(&slots[tid]);
                const int v1 = ld_slot(&slots[tid + 64]);
                const int v2 = ld_slot(&slots[tid + 128]);
                const int v3 = ld_slot(&slots[tid + 192]);
                const bool ok = (v0 >= tgt) & (v1 >= tgt) & (v2 >= tgt) & (v3 >= tgt);
                if (__all(ok)) break;
                __builtin_amdgcn_s_sleep(1);
            }
        }
        __syncthreads();    // whole block released; also a compiler barrier
    }
}

extern "C" void kernel_launch(void* const* d_in, const int* in_sizes, int n_in,
                              void* d_out, int out_size, void* d_ws, size_t ws_size,
                              hipStream_t stream) {
    (void)in_sizes; (void)n_in; (void)out_size; (void)ws_size;
    const float* x    = (const float*)d_in[0];
    const float* Wih0 = (const float*)d_in[1];
    const float* Whh0 = (const float*)d_in[2];
    const float* bi0  = (const float*)d_in[3];
    const float* bh0  = (const float*)d_in[4];
    const float* Wih1 = (const float*)d_in[5];
    const float* Whh1 = (const float*)d_in[6];
    const float* bi1  = (const float*)d_in[7];
    const float* bh1  = (const float*)d_in[8];
    float* out = (float*)d_out;
    float* ws  = (float*)d_ws;

    // ws layout (floats): h0T pp [2][32768] | c0 [32768] | h1T pp [2][32768] | c1 [32768] | slots
    float* h0T   = ws;
    float* c0    = ws + 65536;
    float* h1T   = ws + 98304;
    float* c1    = ws + 163840;
    int*   slots = (int*)(ws + 196608);

    // zero state + barrier slots (ws is re-poisoned 0xAA before every timed call)
    hipMemsetAsync(d_ws, 0, 196608 * sizeof(float) + 4096, stream);

    void* args[] = {
        (void*)&x, (void*)&Wih0, (void*)&Whh0, (void*)&bi0, (void*)&bh0,
        (void*)&Wih1, (void*)&Whh1, (void*)&bi1, (void*)&bh1,
        (void*)&h0T, (void*)&c0, (void*)&h1T, (void*)&c1,
        (void*)&out, (void*)&slots
    };
    hipLaunchCooperativeKernel((const void*)lstm_persist, dim3(NB), dim3(512),
                               args, 0, stream);
}

// Round 5
// 8243.539 us; speedup vs baseline: 2.6091x; 2.6091x over previous
//
#include <hip/hip_runtime.h>
#include <math.h>

// 2-layer LSTM, B=64, T=512, F=256, H=512, fp32 — persistent cooperative kernel.
// R5: MFMA path. R1-R4 were all weight-operand-delivery-bound (s_load: ~36us/step;
// LDS ds_read_b128: ~20us/step of LDS issue). Fix: weights live in VGPRs as
// step-invariant bf16 hi/lo MFMA B-fragments, loaded ONCE. h crosses blocks as
// packed (lo16|hi16) bf16-pair uints via relaxed AGENT-scope atomics (coherent
// at L3, no cache flush). Precision: h and W both split hi+lo bf16; 3 MFMAs per
// K=32 chunk (hi*hi, hi*lo, lo*hi) -> ~fp32 accuracy, fp32 accumulate.
// c-state lives in REGISTERS (thread (b,ul) owns c[b][u] across all steps).
// Barrier: all-report slots with per-group targets; h0 ring depth 4 gives
// layer0 two steps of slack over layer1 (WAR-safe, absorbs jitter).
//
// Partition: blocks[0,128)=layer0, [128,256)=layer1; block = 4 hidden units
// (16 gate rows = MFMA N); 512 threads = 8 waves: wave = (mt = m-tile of 16
// batches, kh = K-half). MFMA 16x16x32 bf16: A=h rows (lane&15=batch,
// quad*8+j=k), B=W (lane&15=gate col), C: row=quad*4+reg=batch, col=lane&15.

#define TT 512
#define FF 256
#define HH 512
#define NB 256

typedef __attribute__((ext_vector_type(4)))  float f32x4;
typedef __attribute__((ext_vector_type(8)))  short short8;
typedef __attribute__((ext_vector_type(16))) short short16;

__device__ __forceinline__ float sigmoidf_(float v){ return 1.0f/(1.0f+__expf(-v)); }

__device__ __forceinline__ unsigned short f2bf(float f){          // RTNE fp32->bf16
    unsigned u = __float_as_uint(f);
    u += 0x7FFFu + ((u>>16)&1u);
    return (unsigned short)(u>>16);
}
__device__ __forceinline__ float bf2f(unsigned short h){ return __uint_as_float(((unsigned)h)<<16); }

__device__ __forceinline__ unsigned long long ld8coh(const unsigned* p){
    return __hip_atomic_load((const unsigned long long*)p, __ATOMIC_RELAXED, __HIP_MEMORY_SCOPE_AGENT);
}
__device__ __forceinline__ void st4coh(unsigned* p, unsigned v){
    __hip_atomic_store(p, v, __ATOMIC_RELAXED, __HIP_MEMORY_SCOPE_AGENT);
}
__device__ __forceinline__ int ldslot(const int* p){
    return __hip_atomic_load(p, __ATOMIC_RELAXED, __HIP_MEMORY_SCOPE_AGENT);
}
__device__ __forceinline__ void stslot(int* p, int v){
    __hip_atomic_store(p, v, __ATOMIC_RELAXED, __HIP_MEMORY_SCOPE_AGENT);
}

union HU { unsigned long long q[4]; short16 v; };

__device__ __forceinline__ void split8(const float* v, short8& h8, short8& l8){
#pragma unroll
    for (int j=0;j<8;++j){
        const unsigned short hh = f2bf(v[j]);
        h8[j] = (short)hh;
        l8[j] = (short)f2bf(v[j]-bf2f(hh));
    }
}

#define MFMA(a,b,c) __builtin_amdgcn_mfma_f32_16x16x32_bf16((a),(b),(c),0,0,0)

template<int LAYER>
__device__ __forceinline__ void run(
    const float* __restrict__ x,
    const float* __restrict__ WA, const float* __restrict__ WB,
    const float* __restrict__ bi, const float* __restrict__ bh,
    unsigned* __restrict__ hp0, unsigned* __restrict__ hp1,
    float* __restrict__ out, int* __restrict__ slots,
    const int tile, float (*part)[16][17])
{
    const int tid  = threadIdx.x;
    const int lane = tid & 63;
    const int wv   = __builtin_amdgcn_readfirstlane(tid>>6);
    const int mt   = wv & 3;              // m-tile: batches [16*mt, 16*mt+16)
    const int kh   = wv >> 2;             // K-half
    const int nn   = lane & 15;           // gate col / A batch row within tile
    const int quad = lane >> 4;           // k-octet within chunk
    const int b_m  = mt*16 + nn;          // this lane's A batch row
    const int SA   = (LAYER==0)?FF:HH;    // WA row stride

    // ---- one-time: weight B-fragments (bf16 hi/lo) into registers ----
    short8 wHi[16], wLo[16];
    {
        const int jg = ((nn>>2)<<9) + (tile<<2) + (nn&3);  // gate row for col nn
        const float* rA = WA + (size_t)jg*SA;
        const float* rB = WB + (size_t)jg*HH;
        if (LAYER==1){
            const float* r = kh ? rB : rA;                 // kh=0: Wih1(h0), kh=1: Whh1(h1)
#pragma unroll
            for (int c=0;c<16;++c){
                float v[8]; const float* p = r + c*32 + quad*8;
#pragma unroll
                for(int j=0;j<8;++j) v[j]=p[j];
                split8(v, wHi[c], wLo[c]);
            }
        } else if (kh==0){                                 // 8 x-chunks + 4 h0-chunks
#pragma unroll
            for (int c=0;c<8;++c){
                float v[8]; const float* p = rA + c*32 + quad*8;
#pragma unroll
                for(int j=0;j<8;++j) v[j]=p[j];
                split8(v, wHi[c], wLo[c]);
            }
#pragma unroll
            for (int c=0;c<4;++c){
                float v[8]; const float* p = rB + c*32 + quad*8;
#pragma unroll
                for(int j=0;j<8;++j) v[j]=p[j];
                split8(v, wHi[8+c], wLo[8+c]);
            }
        } else {                                           // 12 h0-chunks (k 128..511)
#pragma unroll
            for (int c=0;c<12;++c){
                float v[8]; const float* p = rB + (c+4)*32 + quad*8;
#pragma unroll
                for(int j=0;j<8;++j) v[j]=p[j];
                split8(v, wHi[c], wLo[c]);
            }
        }
    }

    // ---- epilogue thread state: bias regs + register-resident c ----
    float br[4] = {0,0,0,0}; float creg = 0.f;
    int b_e = 0, ul = 0;
    if (tid < 256){
        b_e = tid>>2; ul = tid&3;                          // lanes grouped by b: 16B h/out bursts
#pragma unroll
        for (int g=0; g<4; ++g){
            const int jgb = (g<<9) + (tile<<2) + ul;
            br[g] = bi[jgb] + bh[jgb];
        }
    }

    const int myblk = blockIdx.x;
    for (int s=0; s<=TT; ++s){
        // ---- dependency wait: L0 slots >= s (both); L1 slots >= s (L1) / s-2 (L0 WAR slack)
        const int tA = s;
        const int tB = (LAYER==0) ? (s-2) : s;
        if (wv==0){
            for(;;){
                const int v0 = ldslot(slots+lane);
                const int v1 = ldslot(slots+lane+64);
                const int v2 = ldslot(slots+lane+128);
                const int v3 = ldslot(slots+lane+192);
                const bool ok = (v0>=tA)&(v1>=tA)&(v2>=tB)&(v3>=tB);
                if (__all(ok)) break;
                __builtin_amdgcn_s_sleep(1);
            }
        }
        __syncthreads();

        const bool active = LAYER ? (s>0) : (s<TT);
        if (active){
            const int t = LAYER ? (s-1) : s;
            f32x4 accH = {0.f,0.f,0.f,0.f};
            f32x4 accM = {0.f,0.f,0.f,0.f};

            if (LAYER==1){
                // kh=0: h0[s-1] (ring slot (s-1)&3); kh=1: h1[s-2] (slot s&1)
                const unsigned* src = kh ? (hp1 + (s&1)*32768)
                                         : (hp0 + (((s-1)&3))*32768);
#pragma unroll
                for (int c=0;c<16;++c){
                    const unsigned* p = src + ((c*4+quad)*64 + b_m)*8;
                    HU u;
                    u.q[0]=ld8coh(p);   u.q[1]=ld8coh(p+2);
                    u.q[2]=ld8coh(p+4); u.q[3]=ld8coh(p+6);
                    const short8 aH = __builtin_shufflevector(u.v,u.v,0,2,4,6,8,10,12,14);
                    const short8 aL = __builtin_shufflevector(u.v,u.v,1,3,5,7,9,11,13,15);
                    accH = MFMA(aH, wHi[c], accH);
                    accM = MFMA(aH, wLo[c], accM);
                    accM = MFMA(aL, wHi[c], accM);
                }
            } else {
                const unsigned* src = hp0 + ((s+3)&3)*32768;   // h0[s-1]
                if (kh==0){
                    const float* xp = x + ((size_t)b_m*TT + t)*FF + quad*8;
#pragma unroll
                    for (int c=0;c<8;++c){
                        float v[8];
                        const float4 a0 = *(const float4*)(xp + c*32);
                        const float4 a1 = *(const float4*)(xp + c*32 + 4);
                        v[0]=a0.x; v[1]=a0.y; v[2]=a0.z; v[3]=a0.w;
                        v[4]=a1.x; v[5]=a1.y; v[6]=a1.z; v[7]=a1.w;
                        short8 aH, aL; split8(v, aH, aL);
                        accH = MFMA(aH, wHi[c], accH);
                        accM = MFMA(aH, wLo[c], accM);
                        accM = MFMA(aL, wHi[c], accM);
                    }
#pragma unroll
                    for (int c=0;c<4;++c){
                        const unsigned* p = src + ((c*4+quad)*64 + b_m)*8;
                        HU u;
                        u.q[0]=ld8coh(p);   u.q[1]=ld8coh(p+2);
                        u.q[2]=ld8coh(p+4); u.q[3]=ld8coh(p+6);
                        const short8 aH = __builtin_shufflevector(u.v,u.v,0,2,4,6,8,10,12,14);
                        const short8 aL = __builtin_shufflevector(u.v,u.v,1,3,5,7,9,11,13,15);
                        accH = MFMA(aH, wHi[8+c], accH);
                        accM = MFMA(aH, wLo[8+c], accM);
                        accM = MFMA(aL, wHi[8+c], accM);
                    }
                } else {
#pragma unroll
                    for (int c=0;c<12;++c){
                        const unsigned* p = src + (((c+4)*4+quad)*64 + b_m)*8;
                        HU u;
                        u.q[0]=ld8coh(p);   u.q[1]=ld8coh(p+2);
                        u.q[2]=ld8coh(p+4); u.q[3]=ld8coh(p+6);
                        const short8 aH = __builtin_shufflevector(u.v,u.v,0,2,4,6,8,10,12,14);
                        const short8 aL = __builtin_shufflevector(u.v,u.v,1,3,5,7,9,11,13,15);
                        accH = MFMA(aH, wHi[c], accH);
                        accM = MFMA(aH, wLo[c], accM);
                        accM = MFMA(aL, wHi[c], accM);
                    }
                }
            }

            // ---- combine K-halves via LDS, then fused gate epilogue ----
#pragma unroll
            for (int r=0;r<4;++r)
                part[kh*4+mt][quad*4+r][nn] = accH[r]+accM[r];
            __syncthreads();
            if (tid < 256){
                const int mte = b_e>>4, mr = b_e&15;
                float pre[4];
#pragma unroll
                for (int g=0; g<4; ++g){
                    const int col = (g<<2)+ul;
                    pre[g] = part[mte][mr][col] + part[4+mte][mr][col] + br[g];
                }
                const float iv = sigmoidf_(pre[0]);
                const float fv = sigmoidf_(pre[1]);
                const float gv = tanhf(pre[2]);
                const float ov = sigmoidf_(pre[3]);
                creg = fv*creg + iv*gv;                      // c in a register!
                const float hn = ov * tanhf(creg);
                const unsigned short hh = f2bf(hn);
                const unsigned short hl = f2bf(hn - bf2f(hh));
                const unsigned pk = ((unsigned)hl<<16) | (unsigned)hh;
                const int u   = (tile<<2) + ul;
                const int idx = ((u>>3)*64 + b_e)*8 + (u&7); // hA[koct][b][8] pairs
                if (LAYER==0) st4coh(hp0 + (s&3)*32768 + idx, pk);
                else {
                    st4coh(hp1 + ((s-1)&1)*32768 + idx, pk);
                    out[((size_t)b_e*TT + t)*HH + u] = hn;   // fp32, plain cached
                }
            }
        }

        // ---- publish progress: vmcnt(0) drain in syncthreads acks coherent
        // h stores before the token store issues ----
        __syncthreads();
        if (tid==0) stslot(slots + myblk, s+1);
    }
}

__global__ void __launch_bounds__(512,2) lstm_persist(
    const float* __restrict__ x,
    const float* __restrict__ Wih0, const float* __restrict__ Whh0,
    const float* __restrict__ bi0,  const float* __restrict__ bh0,
    const float* __restrict__ Wih1, const float* __restrict__ Whh1,
    const float* __restrict__ bi1,  const float* __restrict__ bh1,
    unsigned* hp0, unsigned* hp1, float* out, int* slots)
{
    __shared__ float part[8][16][17];
    const int layer = blockIdx.x>>7, tile = blockIdx.x&127;
    if (layer==0) run<0>(x, Wih0, Whh0, bi0, bh0, hp0, hp1, out, slots, tile, part);
    else          run<1>(x, Wih1, Whh1, bi1, bh1, hp0, hp1, out, slots, tile, part);
}

extern "C" void kernel_launch(void* const* d_in, const int* in_sizes, int n_in,
                              void* d_out, int out_size, void* d_ws, size_t ws_size,
                              hipStream_t stream) {
    (void)in_sizes; (void)n_in; (void)out_size; (void)ws_size;
    const float* x    = (const float*)d_in[0];
    const float* Wih0 = (const float*)d_in[1];
    const float* Whh0 = (const float*)d_in[2];
    const float* bi0  = (const float*)d_in[3];
    const float* bh0  = (const float*)d_in[4];
    const float* Wih1 = (const float*)d_in[5];
    const float* Whh1 = (const float*)d_in[6];
    const float* bi1  = (const float*)d_in[7];
    const float* bh1  = (const float*)d_in[8];
    float* out = (float*)d_out;
    unsigned* ws = (unsigned*)d_ws;

    // ws (uints): hp0 ring[4][32768] | hp1 ring[2][32768] | slots[256]
    unsigned* hp0 = ws;                   // 4 slots x 128KB
    unsigned* hp1 = ws + 4*32768;         // 2 slots x 128KB
    int* slots    = (int*)(ws + 6*32768);

    hipMemsetAsync(d_ws, 0, (6*32768 + 256)*sizeof(unsigned), stream);

    void* args[] = {
        (void*)&x, (void*)&Wih0, (void*)&Whh0, (void*)&bi0, (void*)&bh0,
        (void*)&Wih1, (void*)&Whh1, (void*)&bi1, (void*)&bh1,
        (void*)&hp0, (void*)&hp1, (void*)&out, (void*)&slots
    };
    hipLaunchCooperativeKernel((const void*)lstm_persist, dim3(NB), dim3(512),
                               args, 0, stream);
}